// Round 1
// 117.228 us; speedup vs baseline: 1.0278x; 1.0278x over previous
//
#include <hip/hip_runtime.h>
#include <stdint.h>

#define BATCH 16384
#define MAXA 32
#define FEAT 768
#define HIDDEN 1024

// ---------------------------------------------------------------------------
// Fused prep: per-h absmax -> scale, quantize to u8 (biased +128), transpose
// through a small LDS tile, write wQ[f][h] in 8-byte chunks.
// 128 blocks x 256 threads; block owns 8 hidden rows (h0..h0+7).
// Thread layout: hloc = tid>>5 (0..7), l32 = tid&31 covers f in 32-strides.
// ---------------------------------------------------------------------------
__global__ __launch_bounds__(256) void prep_quant(const float* __restrict__ ftw,
                                                  uint8_t* __restrict__ wQ,
                                                  float* __restrict__ scale) {
  const int h0 = blockIdx.x * 8;
  const int hloc = threadIdx.x >> 5;   // 0..7
  const int l32 = threadIdx.x & 31;    // 0..31
  const int h = h0 + hloc;

  float w[24];
  float amax = 0.f;
  const float* __restrict__ src = ftw + (size_t)h * FEAT;
#pragma unroll
  for (int k = 0; k < 24; ++k) {
    w[k] = src[l32 + 32 * k];
    amax = fmaxf(amax, fabsf(w[k]));
  }
  // reduce absmax across the 32 lanes that share this h (masks <=16 stay
  // inside the 32-lane half of the wave)
#pragma unroll
  for (int m = 1; m <= 16; m <<= 1)
    amax = fmaxf(amax, __shfl_xor(amax, m, 64));
  amax = fmaxf(amax, 1e-20f);
  if (l32 == 0) scale[h] = amax / 127.f;
  const float inv = 127.f / amax;

  __shared__ __align__(16) uint8_t tile[FEAT * 8];  // [f][hloc], 6 KB
#pragma unroll
  for (int k = 0; k < 24; ++k) {
    int q = __float2int_rn(w[k] * inv);             // [-127,127]
    tile[(l32 + 32 * k) * 8 + hloc] = (uint8_t)(q + 128);
  }
  __syncthreads();

  // coalesced-ish transpose-out: 8 B per f row, 3 rows per thread
#pragma unroll
  for (int p = 0; p < 3; ++p) {
    int f = threadIdx.x + 256 * p;
    unsigned long long v = *(const unsigned long long*)&tile[f * 8];
    *(unsigned long long*)(wQ + (size_t)f * HIDDEN + h0) = v;
  }

  // dummy zero column f=768 (q=0 biased -> 0x80), for invalid/dup features
  if (blockIdx.x == 0)
    ((uint32_t*)(wQ + (size_t)FEAT * HIDDEN))[threadIdx.x] = 0x80808080u;
}

// unpack a u32 (4 u8, h-consecutive) into two u16-pairs and accumulate.
// Plain u32 add == packed u16 add: field max = 32*255 = 8160, never carries.
__device__ __forceinline__ void acc16(uint32_t* acc, uint4 w) {
  acc[0] += __builtin_amdgcn_perm(0u, w.x, 0x0c010c00u);
  acc[1] += __builtin_amdgcn_perm(0u, w.x, 0x0c030c02u);
  acc[2] += __builtin_amdgcn_perm(0u, w.y, 0x0c010c00u);
  acc[3] += __builtin_amdgcn_perm(0u, w.y, 0x0c030c02u);
  acc[4] += __builtin_amdgcn_perm(0u, w.z, 0x0c010c00u);
  acc[5] += __builtin_amdgcn_perm(0u, w.z, 0x0c030c02u);
  acc[6] += __builtin_amdgcn_perm(0u, w.w, 0x0c010c00u);
  acc[7] += __builtin_amdgcn_perm(0u, w.w, 0x0c030c02u);
}

// One wave per batch row. Lane L owns h = L*16 .. +15 for BOTH sides.
// Branch-free gather with an 8-deep software-prefetch ring (16 uint4 loads in
// flight) so the L2 latency (~200 cy) is covered by >8 outstanding requests
// per wave instead of ~2 (the VGPR=44 register-minimized schedule).
__global__ __launch_bounds__(256, 3) void nn_fwd(
    const int* __restrict__ stm, const int* __restrict__ nstm,
    const uint8_t* __restrict__ wQ, const float* __restrict__ scale,
    const float* __restrict__ bias, const float* __restrict__ outw,
    const float* __restrict__ outb, float* __restrict__ out)
{
  const int lane = threadIdx.x & 63;
  const int row  = blockIdx.x * 4 + (threadIdx.x >> 6);
  const int half = lane >> 5;       // 0 = stm, 1 = nstm
  const int pos  = lane & 31;

  const int* __restrict__ src = half ? nstm : stm;
  int idx = src[row * MAXA + pos];
  bool valid = idx >= 0;            // -1 padding -> no contribution
  // dedupe within each half: reference .at[].max() counts duplicates once
#pragma unroll
  for (int j = 0; j < 31; ++j) {
    int other = __shfl(idx, (half << 5) | j, 64);
    if (j < pos && other == idx) valid = false;
  }
  const int fmap = valid ? idx : FEAT;   // dummy zero column

  uint32_t accs[8], accn[8];
#pragma unroll
  for (int k = 0; k < 8; ++k) { accs[k] = 0u; accn[k] = 0u; }

  // 8-deep prefetch ring: prologue issues j=0..7 for both sides.
  uint4 bs[8], bn[8];
#pragma unroll
  for (int j = 0; j < 8; ++j) {
    int fs_ = __builtin_amdgcn_readlane(fmap, j);
    int fn_ = __builtin_amdgcn_readlane(fmap, 32 + j);
    bs[j] = ((const uint4*)(wQ + (size_t)fs_ * HIDDEN))[lane];
    bn[j] = ((const uint4*)(wQ + (size_t)fn_ * HIDDEN))[lane];
  }
#pragma unroll
  for (int j = 0; j < 32; ++j) {
    uint4 ws_ = bs[j & 7];
    uint4 wn_ = bn[j & 7];
    if (j < 24) {   // steady state: issue loads 8 iterations ahead
      int fs_ = __builtin_amdgcn_readlane(fmap, j + 8);
      int fn_ = __builtin_amdgcn_readlane(fmap, 32 + j + 8);
      bs[j & 7] = ((const uint4*)(wQ + (size_t)fs_ * HIDDEN))[lane];
      bn[j & 7] = ((const uint4*)(wQ + (size_t)fn_ * HIDDEN))[lane];
    }
    acc16(accs, ws_);
    acc16(accn, wn_);
  }

  // Every position contributes +128 per element: de-bias is constant 32*128.
  const int DB = 32 * 128;

  // Epilogue: dequant + bias + clip01, fused 2048-dot with out_w, sigmoid.
  const int hbase = lane * 16;
  float sc[16], bb[16], ows[16], own[16];
  {
    const float4* s4 = (const float4*)(scale + hbase);
    const float4* b4 = (const float4*)(bias + hbase);
    const float4* oS = (const float4*)(outw + hbase);
    const float4* oN = (const float4*)(outw + HIDDEN + hbase);
#pragma unroll
    for (int q = 0; q < 4; ++q) {
      float4 v;
      v = s4[q]; sc[4*q]=v.x; sc[4*q+1]=v.y; sc[4*q+2]=v.z; sc[4*q+3]=v.w;
      v = b4[q]; bb[4*q]=v.x; bb[4*q+1]=v.y; bb[4*q+2]=v.z; bb[4*q+3]=v.w;
      v = oS[q]; ows[4*q]=v.x; ows[4*q+1]=v.y; ows[4*q+2]=v.z; ows[4*q+3]=v.w;
      v = oN[q]; own[4*q]=v.x; own[4*q+1]=v.y; own[4*q+2]=v.z; own[4*q+3]=v.w;
    }
  }
  float partial = 0.f;
#pragma unroll
  for (int k = 0; k < 16; ++k) {
    uint32_t as = accs[k >> 1], an = accn[k >> 1];
    int qs = (int)((k & 1) ? (as >> 16) : (as & 0xffffu)) - DB;
    int qn = (int)((k & 1) ? (an >> 16) : (an & 0xffffu)) - DB;
    float hs = fminf(fmaxf(fmaf((float)qs, sc[k], bb[k]), 0.f), 1.f);
    float hn = fminf(fmaxf(fmaf((float)qn, sc[k], bb[k]), 0.f), 1.f);
    partial += hs * ows[k] + hn * own[k];
  }
#pragma unroll
  for (int off = 32; off > 0; off >>= 1)
    partial += __shfl_down(partial, off, 64);
  if (lane == 0) {
    float y = partial + outb[0];
    out[row] = 1.f / (1.f + __expf(-y));
  }
}

extern "C" void kernel_launch(void* const* d_in, const int* in_sizes, int n_in,
                              void* d_out, int out_size, void* d_ws, size_t ws_size,
                              hipStream_t stream) {
  const int*   stm  = (const int*)d_in[0];
  const int*   nstm = (const int*)d_in[1];
  const float* ftw  = (const float*)d_in[2];   // (1024, 768) fp32
  const float* ftb  = (const float*)d_in[3];   // (1024,) fp32
  const float* outw = (const float*)d_in[4];   // (2048,) fp32
  const float* outb = (const float*)d_in[5];   // (1,) fp32

  uint8_t* wQ    = (uint8_t*)d_ws;                               // (768+1)*1024 B
  float*   scale = (float*)(wQ + (size_t)(FEAT + 1) * HIDDEN);   // 4 KB

  prep_quant<<<HIDDEN / 8, 256, 0, stream>>>(ftw, wQ, scale);
  nn_fwd<<<BATCH / 4, 256, 0, stream>>>(stm, nstm, wQ, scale, ftb, outw, outb,
                                        (float*)d_out);
}